// Round 1
// baseline (453.173 us; speedup 1.0000x reference)
//
#include <hip/hip_runtime.h>

typedef __bf16 bf16_t;
typedef __bf16 bf16x8 __attribute__((ext_vector_type(8)));
typedef __bf16 bf16x4v __attribute__((ext_vector_type(4)));
typedef float floatx4 __attribute__((ext_vector_type(4)));

#define MFMA16(a, b, c) __builtin_amdgcn_mfma_f32_16x16x32_bf16((a), (b), (c), 0, 0, 0)

constexpr int S_ = 2048;
constexpr int HID_ = 1024;
constexpr int HH = 16;
constexpr int DD = 64;

// ---------------------------------------------------------------- cvt dist_emb
__global__ __launch_bounds__(256) void cvt_e_kernel(const float* __restrict__ src,
                                                    bf16_t* __restrict__ dst, int n) {
  int i = blockIdx.x * 256 + threadIdx.x;
  if (i < n) dst[i] = (bf16_t)src[i];
}

// ---------------------------------------------------------------- QKV GEMM
// out = X @ W^T + bias, X:[4096,1024] fp32, W:[1024,1024] fp32 (row o, k-contig)
// transposed==0: out[b,h,s,d] bf16;  transposed==1: out[b,h,d,s] bf16
__global__ __launch_bounds__(256) void qkv_gemm_kernel(
    const float* __restrict__ X, const float* __restrict__ W,
    const float* __restrict__ bias, bf16_t* __restrict__ out, int transposed) {
  __shared__ alignas(16) bf16_t As[128][40];
  __shared__ alignas(16) bf16_t Bs[128][40];
  const int tid = threadIdx.x;
  const int lane = tid & 63, wid = tid >> 6;
  const int l15 = lane & 15, quad = lane >> 4;
  const int m0 = blockIdx.x * 128, n0 = blockIdx.y * 128;
  const int wm = (wid >> 1) * 64, wn = (wid & 1) * 64;
  floatx4 acc[4][4] = {};
  const int srow = tid >> 1, scol = (tid & 1) * 16;
  const float* aptr = X + (size_t)(m0 + srow) * HID_ + scol;
  const float* bptr = W + (size_t)(n0 + srow) * HID_ + scol;

  for (int k0 = 0; k0 < HID_; k0 += 32) {
    __syncthreads();
    {
      const float4* a4 = (const float4*)(aptr + k0);
      float4 f0 = a4[0], f1 = a4[1], f2 = a4[2], f3 = a4[3];
      bf16x4v p0 = {(bf16_t)f0.x, (bf16_t)f0.y, (bf16_t)f0.z, (bf16_t)f0.w};
      bf16x4v p1 = {(bf16_t)f1.x, (bf16_t)f1.y, (bf16_t)f1.z, (bf16_t)f1.w};
      bf16x4v p2 = {(bf16_t)f2.x, (bf16_t)f2.y, (bf16_t)f2.z, (bf16_t)f2.w};
      bf16x4v p3 = {(bf16_t)f3.x, (bf16_t)f3.y, (bf16_t)f3.z, (bf16_t)f3.w};
      *(bf16x4v*)&As[srow][scol + 0] = p0;
      *(bf16x4v*)&As[srow][scol + 4] = p1;
      *(bf16x4v*)&As[srow][scol + 8] = p2;
      *(bf16x4v*)&As[srow][scol + 12] = p3;
      const float4* b4 = (const float4*)(bptr + k0);
      float4 g0 = b4[0], g1 = b4[1], g2 = b4[2], g3 = b4[3];
      bf16x4v q0 = {(bf16_t)g0.x, (bf16_t)g0.y, (bf16_t)g0.z, (bf16_t)g0.w};
      bf16x4v q1 = {(bf16_t)g1.x, (bf16_t)g1.y, (bf16_t)g1.z, (bf16_t)g1.w};
      bf16x4v q2 = {(bf16_t)g2.x, (bf16_t)g2.y, (bf16_t)g2.z, (bf16_t)g2.w};
      bf16x4v q3 = {(bf16_t)g3.x, (bf16_t)g3.y, (bf16_t)g3.z, (bf16_t)g3.w};
      *(bf16x4v*)&Bs[srow][scol + 0] = q0;
      *(bf16x4v*)&Bs[srow][scol + 4] = q1;
      *(bf16x4v*)&Bs[srow][scol + 8] = q2;
      *(bf16x4v*)&Bs[srow][scol + 12] = q3;
    }
    __syncthreads();
    bf16x8 af[4], bfv[4];
#pragma unroll
    for (int t = 0; t < 4; ++t) af[t] = *(const bf16x8*)&As[wm + t * 16 + l15][quad * 8];
#pragma unroll
    for (int t = 0; t < 4; ++t) bfv[t] = *(const bf16x8*)&Bs[wn + t * 16 + l15][quad * 8];
#pragma unroll
    for (int mt = 0; mt < 4; ++mt)
#pragma unroll
      for (int nt = 0; nt < 4; ++nt)
        acc[mt][nt] = MFMA16(af[mt], bfv[nt], acc[mt][nt]);
  }

#pragma unroll
  for (int nt = 0; nt < 4; ++nt) {
    int o = n0 + wn + nt * 16 + l15;
    float bv = bias[o];
    int h = o >> 6, d = o & 63;
#pragma unroll
    for (int mt = 0; mt < 4; ++mt) {
      int sb = m0 + wm + mt * 16 + quad * 4;
      int b = sb >> 11, s = sb & 2047;
      if (!transposed) {
        bf16_t* dst = out + (((size_t)(b * HH + h) * S_ + s) * DD + d);
#pragma unroll
        for (int i = 0; i < 4; ++i) dst[(size_t)i * DD] = (bf16_t)(acc[mt][nt][i] + bv);
      } else {
        bf16_t* dst = out + (((size_t)(b * HH + h) * DD + d) * S_ + s);
        bf16x4v pk = {(bf16_t)(acc[mt][nt][0] + bv), (bf16_t)(acc[mt][nt][1] + bv),
                      (bf16_t)(acc[mt][nt][2] + bv), (bf16_t)(acc[mt][nt][3] + bv)};
        *(bf16x4v*)dst = pk;
      }
    }
  }
}

// ---------------------------------------------------------------- fused attention
// Q,K: [B,H,S,D] bf16; Vt: [B,H,D,S] bf16; E: [4095,64] bf16; mask: [B,1,1,S] fp32
// out: [B,S,H*D] fp32
__global__ __launch_bounds__(256) void attn_kernel(
    const bf16_t* __restrict__ Q, const bf16_t* __restrict__ K,
    const bf16_t* __restrict__ Vt, const bf16_t* __restrict__ E,
    const float* __restrict__ mask, float* __restrict__ out) {
  __shared__ alignas(16) bf16_t Qs[64][72];
  __shared__ alignas(16) bf16_t Ks[64][72];
  __shared__ alignas(16) bf16_t Vs[64][72];
  __shared__ alignas(16) bf16_t EsPs[128 * 72];  // union: Es[128][72] (phase2) / Ps[64][72] (phase3/4)
  __shared__ alignas(16) bf16_t T1t[128][68];    // T1t[w][l-row]
  __shared__ alignas(16) bf16_t T2t[128][68];    // T2t[w][r-row]
  __shared__ float mask_s[64];
  auto Es = (bf16_t(*)[72])EsPs;
  auto Ps = (bf16_t(*)[72])EsPs;

  const int tid = threadIdx.x;
  const int lane = tid & 63, wid = tid >> 6;
  const int l15 = lane & 15, quad = lane >> 4;
  const int bidx = blockIdx.x;
  const int lblk = bidx & 31, bh = bidx >> 5;  // bh = b*16+h
  const int l0 = lblk * 64;
  const bf16_t* Qb = Q + (size_t)bh * S_ * DD;
  const bf16_t* Kb = K + (size_t)bh * S_ * DD;
  const bf16_t* Vb = Vt + (size_t)bh * DD * S_;
  const float* maskb = mask + (size_t)(bh >> 4) * S_;

  {  // stage Q tile [64][64]
    int row = tid >> 2, cs = (tid & 3) * 16;
    const float4* src = (const float4*)(Qb + (size_t)(l0 + row) * DD + cs);
    *(float4*)&Qs[row][cs] = src[0];
    *(float4*)&Qs[row][cs + 8] = src[1];
  }
  __syncthreads();
  const bf16x8 qf0 = *(const bf16x8*)&Qs[wid * 16 + l15][quad * 8];
  const bf16x8 qf1 = *(const bf16x8*)&Qs[wid * 16 + l15][32 + quad * 8];

  floatx4 Oacc[4] = {};
  float mrow[4] = {-INFINITY, -INFINITY, -INFINITY, -INFINITY};
  float lrow[4] = {0.f, 0.f, 0.f, 0.f};

  for (int r0 = 0; r0 < S_; r0 += 64) {
    __syncthreads();
    {  // stage K rows [r][d] and V rows [d][r]
      int row = tid >> 2, cs = (tid & 3) * 16;
      const float4* ks = (const float4*)(Kb + (size_t)(r0 + row) * DD + cs);
      *(float4*)&Ks[row][cs] = ks[0];
      *(float4*)&Ks[row][cs + 8] = ks[1];
      const float4* vs = (const float4*)(Vb + (size_t)row * S_ + r0 + cs);
      *(float4*)&Vs[row][cs] = vs[0];
      *(float4*)&Vs[row][cs + 8] = vs[1];
    }
    {  // stage E window: Es[w] = E[l0-r0+1984+w], w in [0,128)
      int w = tid >> 1, cs2 = (tid & 1) * 32;
      int eidx = l0 - r0 + 1984 + w;
      if (eidx > 4094) eidx = 4094;  // w=127 never gathered
      const float4* es = (const float4*)(E + (size_t)eidx * DD + cs2);
      *(float4*)&Es[w][cs2] = es[0];
      *(float4*)&Es[w][cs2 + 8] = es[1];
      *(float4*)&Es[w][cs2 + 16] = es[2];
      *(float4*)&Es[w][cs2 + 24] = es[3];
    }
    if (tid < 64) mask_s[tid] = maskb[r0 + tid];
    __syncthreads();

    // phase 2: T1 = Q_tile·Ew^T, T2 = K_tile·Ew^T  (each wave: its 16-row stripe)
    {
      bf16x8 kf0 = *(const bf16x8*)&Ks[wid * 16 + l15][quad * 8];
      bf16x8 kf1 = *(const bf16x8*)&Ks[wid * 16 + l15][32 + quad * 8];
#pragma unroll
      for (int wt = 0; wt < 8; ++wt) {
        bf16x8 e0 = *(const bf16x8*)&Es[wt * 16 + l15][quad * 8];
        bf16x8 e1 = *(const bf16x8*)&Es[wt * 16 + l15][32 + quad * 8];
        floatx4 t1 = {}, t2 = {};
        t1 = MFMA16(qf0, e0, t1);
        t1 = MFMA16(qf1, e1, t1);
        t2 = MFMA16(kf0, e0, t2);
        t2 = MFMA16(kf1, e1, t2);
        bf16x4v p1 = {(bf16_t)t1[0], (bf16_t)t1[1], (bf16_t)t1[2], (bf16_t)t1[3]};
        bf16x4v p2 = {(bf16_t)t2[0], (bf16_t)t2[1], (bf16_t)t2[2], (bf16_t)t2[3]};
        *(bf16x4v*)&T1t[wt * 16 + l15][wid * 16 + quad * 4] = p1;
        *(bf16x4v*)&T2t[wt * 16 + l15][wid * 16 + quad * 4] = p2;
      }
    }
    __syncthreads();

    // phase 3: scores = (QK^T + rel_q + rel_k)/8 + mask, online softmax
    floatx4 sc[4];
#pragma unroll
    for (int ct = 0; ct < 4; ++ct) {
      bf16x8 b0 = *(const bf16x8*)&Ks[ct * 16 + l15][quad * 8];
      bf16x8 b1 = *(const bf16x8*)&Ks[ct * 16 + l15][32 + quad * 8];
      floatx4 s = {};
      s = MFMA16(qf0, b0, s);
      s = MFMA16(qf1, b1, s);
      int ca = ct * 16 + l15;
#pragma unroll
      for (int i = 0; i < 4; ++i) {
        int ra = wid * 16 + quad * 4 + i;
        int w = ra - ca + 63;  // in [0,126]
        s[i] = (s[i] + (float)T1t[w][ra] + (float)T2t[w][ca]) * 0.125f + mask_s[ca];
      }
      sc[ct] = s;
    }
#pragma unroll
    for (int i = 0; i < 4; ++i) {
      float mx = fmaxf(fmaxf(sc[0][i], sc[1][i]), fmaxf(sc[2][i], sc[3][i]));
      mx = fmaxf(mx, __shfl_xor(mx, 1));
      mx = fmaxf(mx, __shfl_xor(mx, 2));
      mx = fmaxf(mx, __shfl_xor(mx, 4));
      mx = fmaxf(mx, __shfl_xor(mx, 8));
      float mnew = fmaxf(mrow[i], mx);
      float alpha = __expf(mrow[i] - mnew);
      mrow[i] = mnew;
      float rs = 0.f;
#pragma unroll
      for (int ct = 0; ct < 4; ++ct) {
        float p = __expf(sc[ct][i] - mnew);
        sc[ct][i] = p;
        rs += p;
      }
      rs += __shfl_xor(rs, 1);
      rs += __shfl_xor(rs, 2);
      rs += __shfl_xor(rs, 4);
      rs += __shfl_xor(rs, 8);
      lrow[i] = lrow[i] * alpha + rs;
#pragma unroll
      for (int dt = 0; dt < 4; ++dt) Oacc[dt][i] *= alpha;
    }
    // write P (C-layout -> A-layout via LDS; aliases Es, safe: phase-2 barrier passed)
#pragma unroll
    for (int ct = 0; ct < 4; ++ct)
#pragma unroll
      for (int i = 0; i < 4; ++i)
        Ps[wid * 16 + quad * 4 + i][ct * 16 + l15] = (bf16_t)sc[ct][i];
    __syncthreads();

    // phase 4: O += P · V
    {
      bf16x8 pf0 = *(const bf16x8*)&Ps[wid * 16 + l15][quad * 8];
      bf16x8 pf1 = *(const bf16x8*)&Ps[wid * 16 + l15][32 + quad * 8];
#pragma unroll
      for (int dt = 0; dt < 4; ++dt) {
        bf16x8 v0 = *(const bf16x8*)&Vs[dt * 16 + l15][quad * 8];
        bf16x8 v1 = *(const bf16x8*)&Vs[dt * 16 + l15][32 + quad * 8];
        Oacc[dt] = MFMA16(pf0, v0, Oacc[dt]);
        Oacc[dt] = MFMA16(pf1, v1, Oacc[dt]);
      }
    }
  }

  // epilogue: out[b, l, h*64+d] = O / l
  const int b = bh >> 4, h = bh & 15;
#pragma unroll
  for (int i = 0; i < 4; ++i) {
    float inv = 1.f / lrow[i];
    int ra = l0 + wid * 16 + quad * 4 + i;
    float* dst = out + (size_t)(b * S_ + ra) * HID_ + h * DD;
#pragma unroll
    for (int dt = 0; dt < 4; ++dt) dst[dt * 16 + l15] = Oacc[dt][i] * inv;
  }
}

// ---------------------------------------------------------------- launch
extern "C" void kernel_launch(void* const* d_in, const int* in_sizes, int n_in,
                              void* d_out, int out_size, void* d_ws, size_t ws_size,
                              hipStream_t stream) {
  const float* hidden = (const float*)d_in[0];
  const float* amask = (const float*)d_in[1];
  const float* Wq = (const float*)d_in[2];
  const float* bq = (const float*)d_in[3];
  const float* Wk = (const float*)d_in[4];
  const float* bk = (const float*)d_in[5];
  const float* Wv = (const float*)d_in[6];
  const float* bv = (const float*)d_in[7];
  const float* de = (const float*)d_in[8];
  float* outp = (float*)d_out;
  char* ws = (char*)d_ws;
  bf16_t* qb = (bf16_t*)(ws);                                // 8 MiB [B,H,S,D]
  bf16_t* kb = (bf16_t*)(ws + (size_t)8 * 1024 * 1024);      // 8 MiB [B,H,S,D]
  bf16_t* vb = (bf16_t*)(ws + (size_t)16 * 1024 * 1024);     // 8 MiB [B,H,D,S]
  bf16_t* eb = (bf16_t*)(ws + (size_t)24 * 1024 * 1024);     // 512 KiB [4095,64]

  cvt_e_kernel<<<dim3(1024), 256, 0, stream>>>(de, eb, 4095 * 64);
  dim3 g(32, 8);
  qkv_gemm_kernel<<<g, 256, 0, stream>>>(hidden, Wq, bq, qb, 0);
  qkv_gemm_kernel<<<g, 256, 0, stream>>>(hidden, Wk, bk, kb, 0);
  qkv_gemm_kernel<<<g, 256, 0, stream>>>(hidden, Wv, bv, vb, 1);
  attn_kernel<<<dim3(1024), 256, 0, stream>>>(qb, kb, vb, eb, amask, outp);
}

// Round 2
// 452.356 us; speedup vs baseline: 1.0018x; 1.0018x over previous
//
#include <hip/hip_runtime.h>

typedef __bf16 bf16_t;
typedef __bf16 bf16x8 __attribute__((ext_vector_type(8)));
typedef __bf16 bf16x4v __attribute__((ext_vector_type(4)));
typedef float floatx4 __attribute__((ext_vector_type(4)));

#define MFMA16(a, b, c) __builtin_amdgcn_mfma_f32_16x16x32_bf16((a), (b), (c), 0, 0, 0)

constexpr int S_ = 2048;
constexpr int HID_ = 1024;
constexpr int HH = 16;
constexpr int DD = 64;

// ---------------------------------------------------------------- generic fp32->bf16 cvt (n % 4 == 0)
__global__ __launch_bounds__(256) void cvt4_kernel(const float* __restrict__ src,
                                                   bf16_t* __restrict__ dst, int n) {
  int i = (blockIdx.x * 256 + threadIdx.x) * 4;
  if (i < n) {
    float4 f = *(const float4*)(src + i);
    bf16x4v p = {(bf16_t)f.x, (bf16_t)f.y, (bf16_t)f.z, (bf16_t)f.w};
    *(bf16x4v*)(dst + i) = p;
  }
}

__global__ __launch_bounds__(256) void cvt_e_kernel(const float* __restrict__ src,
                                                    bf16_t* __restrict__ dst, int n) {
  int i = blockIdx.x * 256 + threadIdx.x;
  if (i < n) dst[i] = (bf16_t)src[i];
}

// ---------------------------------------------------------------- fused QKV GEMM (bf16 inputs)
// hb:[4096,1024] bf16, wb:[3][1024,1024] bf16 (row o, k-contig). z picks W/bias/out.
// z=0,1: out[b,h,s,d]; z=2: out[b,h,d,s]
__global__ __launch_bounds__(256) void qkv_gemm2_kernel(
    const bf16_t* __restrict__ hb, const bf16_t* __restrict__ wb,
    const float* __restrict__ bq, const float* __restrict__ bk, const float* __restrict__ bv,
    bf16_t* __restrict__ qb, bf16_t* __restrict__ kb, bf16_t* __restrict__ vb) {
  __shared__ alignas(16) bf16_t As[128][72];
  __shared__ alignas(16) bf16_t Bs[128][72];
  const int z = blockIdx.z;
  const bf16_t* W = wb + (size_t)z * HID_ * HID_;
  const float* bias = (z == 0) ? bq : (z == 1) ? bk : bv;
  bf16_t* out = (z == 0) ? qb : (z == 1) ? kb : vb;
  const int transposed = (z == 2);

  const int tid = threadIdx.x;
  const int lane = tid & 63, wid = tid >> 6;
  const int l15 = lane & 15, quad = lane >> 4;
  const int m0 = blockIdx.x * 128, n0 = blockIdx.y * 128;
  const int wm = (wid >> 1) * 64, wn = (wid & 1) * 64;
  floatx4 acc[4][4] = {};
  const int srow = tid >> 1, sch = (tid & 1) * 32;
  const bf16_t* aptr = hb + (size_t)(m0 + srow) * HID_ + sch;
  const bf16_t* bptr = W + (size_t)(n0 + srow) * HID_ + sch;

  for (int k0 = 0; k0 < HID_; k0 += 64) {
    __syncthreads();
#pragma unroll
    for (int j = 0; j < 4; ++j) {
      *(bf16x8*)&As[srow][sch + j * 8] = *(const bf16x8*)(aptr + k0 + j * 8);
      *(bf16x8*)&Bs[srow][sch + j * 8] = *(const bf16x8*)(bptr + k0 + j * 8);
    }
    __syncthreads();
    bf16x8 af[4][2], bfv[4][2];
#pragma unroll
    for (int t = 0; t < 4; ++t)
#pragma unroll
      for (int kh = 0; kh < 2; ++kh) {
        af[t][kh] = *(const bf16x8*)&As[wm + t * 16 + l15][kh * 32 + quad * 8];
        bfv[t][kh] = *(const bf16x8*)&Bs[wn + t * 16 + l15][kh * 32 + quad * 8];
      }
#pragma unroll
    for (int mt = 0; mt < 4; ++mt)
#pragma unroll
      for (int nt = 0; nt < 4; ++nt) {
        acc[mt][nt] = MFMA16(af[mt][0], bfv[nt][0], acc[mt][nt]);
        acc[mt][nt] = MFMA16(af[mt][1], bfv[nt][1], acc[mt][nt]);
      }
  }

#pragma unroll
  for (int nt = 0; nt < 4; ++nt) {
    int o = n0 + wn + nt * 16 + l15;
    float bvs = bias[o];
    int h = o >> 6, d = o & 63;
#pragma unroll
    for (int mt = 0; mt < 4; ++mt) {
      int sb = m0 + wm + mt * 16 + quad * 4;
      int b = sb >> 11, s = sb & 2047;
      if (!transposed) {
        bf16_t* dst = out + (((size_t)(b * HH + h) * S_ + s) * DD + d);
#pragma unroll
        for (int i = 0; i < 4; ++i) dst[(size_t)i * DD] = (bf16_t)(acc[mt][nt][i] + bvs);
      } else {
        bf16_t* dst = out + (((size_t)(b * HH + h) * DD + d) * S_ + s);
        bf16x4v pk = {(bf16_t)(acc[mt][nt][0] + bvs), (bf16_t)(acc[mt][nt][1] + bvs),
                      (bf16_t)(acc[mt][nt][2] + bvs), (bf16_t)(acc[mt][nt][3] + bvs)};
        *(bf16x4v*)dst = pk;
      }
    }
  }
}

// ---------------------------------------------------------------- rel_q producer
// T1g[bh][r][l] = q[l] . E[l - r + 2047], l-blocked. A = E-window rows, B = Q rows.
__global__ __launch_bounds__(256) void relq_kernel(const bf16_t* __restrict__ qb,
                                                   const bf16_t* __restrict__ eb,
                                                   bf16_t* __restrict__ T1g) {
  const int tid = threadIdx.x;
  const int lane = tid & 63, wid = tid >> 6;
  const int l15 = lane & 15, quad = lane >> 4;
  const int l0 = blockIdx.x * 64, bh = blockIdx.y;
  const bf16_t* Qb = qb + (size_t)bh * S_ * DD;
  bf16_t* Tb = T1g + (size_t)bh * S_ * S_;

  bf16x8 Bf[4][2];
#pragma unroll
  for (int nt = 0; nt < 4; ++nt)
#pragma unroll
    for (int kh = 0; kh < 2; ++kh)
      Bf[nt][kh] = *(const bf16x8*)&Qb[(size_t)(l0 + nt * 16 + l15) * DD + kh * 32 + quad * 8];

  for (int t = 0; t < 33; ++t) {
    const int mt = wid + 4 * t;  // 0..131, j'-tile
    int arow = l0 + mt * 16 + l15;
    if (arow > 4094) arow = 4094;
    bf16x8 a0 = *(const bf16x8*)&eb[(size_t)arow * DD + quad * 8];
    bf16x8 a1 = *(const bf16x8*)&eb[(size_t)arow * DD + 32 + quad * 8];
    const int jp = mt * 16 + quad * 4;
#pragma unroll
    for (int nt = 0; nt < 4; ++nt) {
      floatx4 acc = {};
      acc = MFMA16(a0, Bf[nt][0], acc);
      acc = MFMA16(a1, Bf[nt][1], acc);
      const int nl = nt * 16 + l15;
      const int rbase = 2047 + nl - jp;
      bf16_t* bp = Tb + (size_t)rbase * S_ + (l0 + nl);
#pragma unroll
      for (int i = 0; i < 4; ++i) {
        int r = rbase - i;
        if (r >= 0 && r < S_) *(bp - (ptrdiff_t)i * S_) = (bf16_t)acc[i];
      }
    }
  }
}

// ---------------------------------------------------------------- rel_k producer
// T2g[bh][r][l] = k[r] . E[l - r + 2047], r-blocked. A = K rows, B = E-window rows.
__global__ __launch_bounds__(256) void relk_kernel(const bf16_t* __restrict__ kb,
                                                   const bf16_t* __restrict__ eb,
                                                   bf16_t* __restrict__ T2g) {
  const int tid = threadIdx.x;
  const int lane = tid & 63, wid = tid >> 6;
  const int l15 = lane & 15, quad = lane >> 4;
  const int r0 = blockIdx.x * 64, bh = blockIdx.y;
  const bf16_t* Kb = kb + (size_t)bh * S_ * DD;
  bf16_t* Tb = T2g + (size_t)bh * S_ * S_;
  const int e0 = 1984 - r0;

  bf16x8 Af[4][2];
#pragma unroll
  for (int mt = 0; mt < 4; ++mt)
#pragma unroll
    for (int kh = 0; kh < 2; ++kh)
      Af[mt][kh] = *(const bf16x8*)&Kb[(size_t)(r0 + mt * 16 + l15) * DD + kh * 32 + quad * 8];

  for (int t = 0; t < 33; ++t) {
    const int nt = wid + 4 * t;  // 0..131, j'-tile
    int erow = e0 + nt * 16 + l15;
    if (erow > 4094) erow = 4094;
    bf16x8 b0 = *(const bf16x8*)&eb[(size_t)erow * DD + quad * 8];
    bf16x8 b1 = *(const bf16x8*)&eb[(size_t)erow * DD + 32 + quad * 8];
    const int nl = nt * 16 + l15;  // j'
#pragma unroll
    for (int mt = 0; mt < 4; ++mt) {
      floatx4 acc = {};
      acc = MFMA16(Af[mt][0], b0, acc);
      acc = MFMA16(Af[mt][1], b1, acc);
      const int mbase = mt * 16 + quad * 4;
      const int lbase = nl + mbase - 63;
      bf16_t* bp = Tb + (size_t)(r0 + mbase) * S_ + lbase;
#pragma unroll
      for (int i = 0; i < 4; ++i) {
        int l = lbase + i;
        if (l >= 0 && l < S_) bp[(ptrdiff_t)i * (S_ + 1)] = (bf16_t)acc[i];
      }
    }
  }
}

// ---------------------------------------------------------------- fused attention v2
// Q,K:[B,H,S,D] bf16; Vt:[B,H,D,S] bf16; T1g,T2g:[B*H,S,S] bf16 ([r][l]); mask fp32
__global__ __launch_bounds__(256) void attn2_kernel(
    const bf16_t* __restrict__ Q, const bf16_t* __restrict__ K,
    const bf16_t* __restrict__ Vt, const bf16_t* __restrict__ T1g,
    const bf16_t* __restrict__ T2g, const float* __restrict__ mask,
    float* __restrict__ out) {
  __shared__ alignas(16) bf16_t Ks[64][72];
  __shared__ alignas(16) bf16_t Vs[64][72];
  __shared__ alignas(16) bf16_t QPs[64][72];  // Q staging, then P tiles
  __shared__ float mask_s[64];

  const int tid = threadIdx.x;
  const int lane = tid & 63, wid = tid >> 6;
  const int l15 = lane & 15, quad = lane >> 4;
  const int bidx = blockIdx.x;
  const int bh = bidx & 31, lblock = bidx >> 5;  // same bh -> same XCD (round-robin)
  const int l0 = lblock * 64;
  const bf16_t* Qb = Q + (size_t)bh * S_ * DD;
  const bf16_t* Kb = K + (size_t)bh * S_ * DD;
  const bf16_t* Vb = Vt + (size_t)bh * DD * S_;
  const bf16_t* T1b = T1g + (size_t)bh * S_ * S_;
  const bf16_t* T2b = T2g + (size_t)bh * S_ * S_;
  const float* maskb = mask + (size_t)(bh >> 4) * S_;

  {  // stage Q tile
    int row = tid >> 2, cs = (tid & 3) * 16;
    const float4* src = (const float4*)(Qb + (size_t)(l0 + row) * DD + cs);
    *(float4*)&QPs[row][cs] = src[0];
    *(float4*)&QPs[row][cs + 8] = src[1];
  }
  __syncthreads();
  const bf16x8 qf0 = *(const bf16x8*)&QPs[wid * 16 + l15][quad * 8];
  const bf16x8 qf1 = *(const bf16x8*)&QPs[wid * 16 + l15][32 + quad * 8];

  const int lcol = l0 + wid * 16 + quad * 4;  // aligned l-base for rel reads

  floatx4 Oacc[4] = {};
  float mrow[4] = {-INFINITY, -INFINITY, -INFINITY, -INFINITY};
  float lrow[4] = {0.f, 0.f, 0.f, 0.f};

  for (int r0 = 0; r0 < S_; r0 += 64) {
    __syncthreads();
    {  // stage K rows [r][d] and V rows [d][r]
      int row = tid >> 2, cs = (tid & 3) * 16;
      const float4* ks = (const float4*)(Kb + (size_t)(r0 + row) * DD + cs);
      *(float4*)&Ks[row][cs] = ks[0];
      *(float4*)&Ks[row][cs + 8] = ks[1];
      const float4* vs = (const float4*)(Vb + (size_t)row * S_ + r0 + cs);
      *(float4*)&Vs[row][cs] = vs[0];
      *(float4*)&Vs[row][cs + 8] = vs[1];
    }
    if (tid < 64) mask_s[tid] = maskb[r0 + tid];
    __syncthreads();

    // prefetch rel tiles (global, vectorized, aligned)
    bf16x4v t1v[4], t2v[4];
#pragma unroll
    for (int ct = 0; ct < 4; ++ct) {
      size_t roff = (size_t)(r0 + ct * 16 + l15) * S_ + lcol;
      t1v[ct] = *(const bf16x4v*)&T1b[roff];
      t2v[ct] = *(const bf16x4v*)&T2b[roff];
    }

    // scores = (QK^T + rel)/8 + mask
    floatx4 sc[4];
#pragma unroll
    for (int ct = 0; ct < 4; ++ct) {
      bf16x8 b0 = *(const bf16x8*)&Ks[ct * 16 + l15][quad * 8];
      bf16x8 b1 = *(const bf16x8*)&Ks[ct * 16 + l15][32 + quad * 8];
      floatx4 s = {};
      s = MFMA16(qf0, b0, s);
      s = MFMA16(qf1, b1, s);
      float mk = mask_s[ct * 16 + l15];
#pragma unroll
      for (int i = 0; i < 4; ++i)
        s[i] = (s[i] + (float)t1v[ct][i] + (float)t2v[ct][i]) * 0.125f + mk;
      sc[ct] = s;
    }
    // online softmax
#pragma unroll
    for (int i = 0; i < 4; ++i) {
      float mx = fmaxf(fmaxf(sc[0][i], sc[1][i]), fmaxf(sc[2][i], sc[3][i]));
      mx = fmaxf(mx, __shfl_xor(mx, 1));
      mx = fmaxf(mx, __shfl_xor(mx, 2));
      mx = fmaxf(mx, __shfl_xor(mx, 4));
      mx = fmaxf(mx, __shfl_xor(mx, 8));
      float mnew = fmaxf(mrow[i], mx);
      float alpha = __expf(mrow[i] - mnew);
      mrow[i] = mnew;
      float rs = 0.f;
#pragma unroll
      for (int ct = 0; ct < 4; ++ct) {
        float p = __expf(sc[ct][i] - mnew);
        sc[ct][i] = p;
        rs += p;
      }
      rs += __shfl_xor(rs, 1);
      rs += __shfl_xor(rs, 2);
      rs += __shfl_xor(rs, 4);
      rs += __shfl_xor(rs, 8);
      lrow[i] = lrow[i] * alpha + rs;
#pragma unroll
      for (int dt = 0; dt < 4; ++dt) Oacc[dt][i] *= alpha;
    }
    // P: C-layout -> A-layout via LDS (QPs reuse; qf regs already loaded)
#pragma unroll
    for (int ct = 0; ct < 4; ++ct)
#pragma unroll
      for (int i = 0; i < 4; ++i)
        QPs[wid * 16 + quad * 4 + i][ct * 16 + l15] = (bf16_t)sc[ct][i];
    __syncthreads();

    // O += P . V
    {
      bf16x8 pf0 = *(const bf16x8*)&QPs[wid * 16 + l15][quad * 8];
      bf16x8 pf1 = *(const bf16x8*)&QPs[wid * 16 + l15][32 + quad * 8];
#pragma unroll
      for (int dt = 0; dt < 4; ++dt) {
        bf16x8 v0 = *(const bf16x8*)&Vs[dt * 16 + l15][quad * 8];
        bf16x8 v1 = *(const bf16x8*)&Vs[dt * 16 + l15][32 + quad * 8];
        Oacc[dt] = MFMA16(pf0, v0, Oacc[dt]);
        Oacc[dt] = MFMA16(pf1, v1, Oacc[dt]);
      }
    }
  }

  const int b = bh >> 4, h = bh & 15;
#pragma unroll
  for (int i = 0; i < 4; ++i) {
    float inv = 1.f / lrow[i];
    int ra = l0 + wid * 16 + quad * 4 + i;
    float* dst = out + (size_t)(b * S_ + ra) * HID_ + h * DD;
#pragma unroll
    for (int dt = 0; dt < 4; ++dt) dst[dt * 16 + l15] = Oacc[dt][i] * inv;
  }
}

// ================================================================ fallback (round-1) path
__global__ __launch_bounds__(256) void qkv_gemm_kernel(
    const float* __restrict__ X, const float* __restrict__ W,
    const float* __restrict__ bias, bf16_t* __restrict__ out, int transposed) {
  __shared__ alignas(16) bf16_t As[128][40];
  __shared__ alignas(16) bf16_t Bs[128][40];
  const int tid = threadIdx.x;
  const int lane = tid & 63, wid = tid >> 6;
  const int l15 = lane & 15, quad = lane >> 4;
  const int m0 = blockIdx.x * 128, n0 = blockIdx.y * 128;
  const int wm = (wid >> 1) * 64, wn = (wid & 1) * 64;
  floatx4 acc[4][4] = {};
  const int srow = tid >> 1, scol = (tid & 1) * 16;
  const float* aptr = X + (size_t)(m0 + srow) * HID_ + scol;
  const float* bptr = W + (size_t)(n0 + srow) * HID_ + scol;

  for (int k0 = 0; k0 < HID_; k0 += 32) {
    __syncthreads();
    {
      const float4* a4 = (const float4*)(aptr + k0);
      float4 f0 = a4[0], f1 = a4[1], f2 = a4[2], f3 = a4[3];
      bf16x4v p0 = {(bf16_t)f0.x, (bf16_t)f0.y, (bf16_t)f0.z, (bf16_t)f0.w};
      bf16x4v p1 = {(bf16_t)f1.x, (bf16_t)f1.y, (bf16_t)f1.z, (bf16_t)f1.w};
      bf16x4v p2 = {(bf16_t)f2.x, (bf16_t)f2.y, (bf16_t)f2.z, (bf16_t)f2.w};
      bf16x4v p3 = {(bf16_t)f3.x, (bf16_t)f3.y, (bf16_t)f3.z, (bf16_t)f3.w};
      *(bf16x4v*)&As[srow][scol + 0] = p0;
      *(bf16x4v*)&As[srow][scol + 4] = p1;
      *(bf16x4v*)&As[srow][scol + 8] = p2;
      *(bf16x4v*)&As[srow][scol + 12] = p3;
      const float4* b4 = (const float4*)(bptr + k0);
      float4 g0 = b4[0], g1 = b4[1], g2 = b4[2], g3 = b4[3];
      bf16x4v q0 = {(bf16_t)g0.x, (bf16_t)g0.y, (bf16_t)g0.z, (bf16_t)g0.w};
      bf16x4v q1 = {(bf16_t)g1.x, (bf16_t)g1.y, (bf16_t)g1.z, (bf16_t)g1.w};
      bf16x4v q2 = {(bf16_t)g2.x, (bf16_t)g2.y, (bf16_t)g2.z, (bf16_t)g2.w};
      bf16x4v q3 = {(bf16_t)g3.x, (bf16_t)g3.y, (bf16_t)g3.z, (bf16_t)g3.w};
      *(bf16x4v*)&Bs[srow][scol + 0] = q0;
      *(bf16x4v*)&Bs[srow][scol + 4] = q1;
      *(bf16x4v*)&Bs[srow][scol + 8] = q2;
      *(bf16x4v*)&Bs[srow][scol + 12] = q3;
    }
    __syncthreads();
    bf16x8 af[4], bfv[4];
#pragma unroll
    for (int t = 0; t < 4; ++t) af[t] = *(const bf16x8*)&As[wm + t * 16 + l15][quad * 8];
#pragma unroll
    for (int t = 0; t < 4; ++t) bfv[t] = *(const bf16x8*)&Bs[wn + t * 16 + l15][quad * 8];
#pragma unroll
    for (int mt = 0; mt < 4; ++mt)
#pragma unroll
      for (int nt = 0; nt < 4; ++nt)
        acc[mt][nt] = MFMA16(af[mt], bfv[nt], acc[mt][nt]);
  }

#pragma unroll
  for (int nt = 0; nt < 4; ++nt) {
    int o = n0 + wn + nt * 16 + l15;
    float bv = bias[o];
    int h = o >> 6, d = o & 63;
#pragma unroll
    for (int mt = 0; mt < 4; ++mt) {
      int sb = m0 + wm + mt * 16 + quad * 4;
      int b = sb >> 11, s = sb & 2047;
      if (!transposed) {
        bf16_t* dst = out + (((size_t)(b * HH + h) * S_ + s) * DD + d);
#pragma unroll
        for (int i = 0; i < 4; ++i) dst[(size_t)i * DD] = (bf16_t)(acc[mt][nt][i] + bv);
      } else {
        bf16_t* dst = out + (((size_t)(b * HH + h) * DD + d) * S_ + s);
        bf16x4v pk = {(bf16_t)(acc[mt][nt][0] + bv), (bf16_t)(acc[mt][nt][1] + bv),
                      (bf16_t)(acc[mt][nt][2] + bv), (bf16_t)(acc[mt][nt][3] + bv)};
        *(bf16x4v*)dst = pk;
      }
    }
  }
}

__global__ __launch_bounds__(256) void attn_kernel(
    const bf16_t* __restrict__ Q, const bf16_t* __restrict__ K,
    const bf16_t* __restrict__ Vt, const bf16_t* __restrict__ E,
    const float* __restrict__ mask, float* __restrict__ out) {
  __shared__ alignas(16) bf16_t Qs[64][72];
  __shared__ alignas(16) bf16_t Ks[64][72];
  __shared__ alignas(16) bf16_t Vs[64][72];
  __shared__ alignas(16) bf16_t EsPs[128 * 72];
  __shared__ alignas(16) bf16_t T1t[128][68];
  __shared__ alignas(16) bf16_t T2t[128][68];
  __shared__ float mask_s[64];
  auto Es = (bf16_t(*)[72])EsPs;
  auto Ps = (bf16_t(*)[72])EsPs;

  const int tid = threadIdx.x;
  const int lane = tid & 63, wid = tid >> 6;
  const int l15 = lane & 15, quad = lane >> 4;
  const int bidx = blockIdx.x;
  const int lblk = bidx & 31, bh = bidx >> 5;
  const int l0 = lblk * 64;
  const bf16_t* Qb = Q + (size_t)bh * S_ * DD;
  const bf16_t* Kb = K + (size_t)bh * S_ * DD;
  const bf16_t* Vb = Vt + (size_t)bh * DD * S_;
  const float* maskb = mask + (size_t)(bh >> 4) * S_;

  {
    int row = tid >> 2, cs = (tid & 3) * 16;
    const float4* src = (const float4*)(Qb + (size_t)(l0 + row) * DD + cs);
    *(float4*)&Qs[row][cs] = src[0];
    *(float4*)&Qs[row][cs + 8] = src[1];
  }
  __syncthreads();
  const bf16x8 qf0 = *(const bf16x8*)&Qs[wid * 16 + l15][quad * 8];
  const bf16x8 qf1 = *(const bf16x8*)&Qs[wid * 16 + l15][32 + quad * 8];

  floatx4 Oacc[4] = {};
  float mrow[4] = {-INFINITY, -INFINITY, -INFINITY, -INFINITY};
  float lrow[4] = {0.f, 0.f, 0.f, 0.f};

  for (int r0 = 0; r0 < S_; r0 += 64) {
    __syncthreads();
    {
      int row = tid >> 2, cs = (tid & 3) * 16;
      const float4* ks = (const float4*)(Kb + (size_t)(r0 + row) * DD + cs);
      *(float4*)&Ks[row][cs] = ks[0];
      *(float4*)&Ks[row][cs + 8] = ks[1];
      const float4* vs = (const float4*)(Vb + (size_t)row * S_ + r0 + cs);
      *(float4*)&Vs[row][cs] = vs[0];
      *(float4*)&Vs[row][cs + 8] = vs[1];
    }
    {
      int w = tid >> 1, cs2 = (tid & 1) * 32;
      int eidx = l0 - r0 + 1984 + w;
      if (eidx > 4094) eidx = 4094;
      const float4* es = (const float4*)(E + (size_t)eidx * DD + cs2);
      *(float4*)&Es[w][cs2] = es[0];
      *(float4*)&Es[w][cs2 + 8] = es[1];
      *(float4*)&Es[w][cs2 + 16] = es[2];
      *(float4*)&Es[w][cs2 + 24] = es[3];
    }
    if (tid < 64) mask_s[tid] = maskb[r0 + tid];
    __syncthreads();

    {
      bf16x8 kf0 = *(const bf16x8*)&Ks[wid * 16 + l15][quad * 8];
      bf16x8 kf1 = *(const bf16x8*)&Ks[wid * 16 + l15][32 + quad * 8];
#pragma unroll
      for (int wt = 0; wt < 8; ++wt) {
        bf16x8 e0 = *(const bf16x8*)&Es[wt * 16 + l15][quad * 8];
        bf16x8 e1 = *(const bf16x8*)&Es[wt * 16 + l15][32 + quad * 8];
        floatx4 t1 = {}, t2 = {};
        t1 = MFMA16(qf0, e0, t1);
        t1 = MFMA16(qf1, e1, t1);
        t2 = MFMA16(kf0, e0, t2);
        t2 = MFMA16(kf1, e1, t2);
        bf16x4v p1 = {(bf16_t)t1[0], (bf16_t)t1[1], (bf16_t)t1[2], (bf16_t)t1[3]};
        bf16x4v p2 = {(bf16_t)t2[0], (bf16_t)t2[1], (bf16_t)t2[2], (bf16_t)t2[3]};
        *(bf16x4v*)&T1t[wt * 16 + l15][wid * 16 + quad * 4] = p1;
        *(bf16x4v*)&T2t[wt * 16 + l15][wid * 16 + quad * 4] = p2;
      }
    }
    __syncthreads();

    floatx4 sc[4];
#pragma unroll
    for (int ct = 0; ct < 4; ++ct) {
      bf16x8 b0 = *(const bf16x8*)&Ks[ct * 16 + l15][quad * 8];
      bf16x8 b1 = *(const bf16x8*)&Ks[ct * 16 + l15][32 + quad * 8];
      floatx4 s = {};
      s = MFMA16(qf0, b0, s);
      s = MFMA16(qf1, b1, s);
      int ca = ct * 16 + l15;
#pragma unroll
      for (int i = 0; i < 4; ++i) {
        int ra = wid * 16 + quad * 4 + i;
        int w = ra - ca + 63;
        s[i] = (s[i] + (float)T1t[w][ra] + (float)T2t[w][ca]) * 0.125f + mask_s[ca];
      }
      sc[ct] = s;
    }
#pragma unroll
    for (int i = 0; i < 4; ++i) {
      float mx = fmaxf(fmaxf(sc[0][i], sc[1][i]), fmaxf(sc[2][i], sc[3][i]));
      mx = fmaxf(mx, __shfl_xor(mx, 1));
      mx = fmaxf(mx, __shfl_xor(mx, 2));
      mx = fmaxf(mx, __shfl_xor(mx, 4));
      mx = fmaxf(mx, __shfl_xor(mx, 8));
      float mnew = fmaxf(mrow[i], mx);
      float alpha = __expf(mrow[i] - mnew);
      mrow[i] = mnew;
      float rs = 0.f;
#pragma unroll
      for (int ct = 0; ct < 4; ++ct) {
        float p = __expf(sc[ct][i] - mnew);
        sc[ct][i] = p;
        rs += p;
      }
      rs += __shfl_xor(rs, 1);
      rs += __shfl_xor(rs, 2);
      rs += __shfl_xor(rs, 4);
      rs += __shfl_xor(rs, 8);
      lrow[i] = lrow[i] * alpha + rs;
#pragma unroll
      for (int dt = 0; dt < 4; ++dt) Oacc[dt][i] *= alpha;
    }
#pragma unroll
    for (int ct = 0; ct < 4; ++ct)
#pragma unroll
      for (int i = 0; i < 4; ++i)
        Ps[wid * 16 + quad * 4 + i][ct * 16 + l15] = (bf16_t)sc[ct][i];
    __syncthreads();

    {
      bf16x8 pf0 = *(const bf16x8*)&Ps[wid * 16 + l15][quad * 8];
      bf16x8 pf1 = *(const bf16x8*)&Ps[wid * 16 + l15][32 + quad * 8];
#pragma unroll
      for (int dt = 0; dt < 4; ++dt) {
        bf16x8 v0 = *(const bf16x8*)&Vs[dt * 16 + l15][quad * 8];
        bf16x8 v1 = *(const bf16x8*)&Vs[dt * 16 + l15][32 + quad * 8];
        Oacc[dt] = MFMA16(pf0, v0, Oacc[dt]);
        Oacc[dt] = MFMA16(pf1, v1, Oacc[dt]);
      }
    }
  }

  const int b = bh >> 4, h = bh & 15;
#pragma unroll
  for (int i = 0; i < 4; ++i) {
    float inv = 1.f / lrow[i];
    int ra = l0 + wid * 16 + quad * 4 + i;
    float* dst = out + (size_t)(b * S_ + ra) * HID_ + h * DD;
#pragma unroll
    for (int dt = 0; dt < 4; ++dt) dst[dt * 16 + l15] = Oacc[dt][i] * inv;
  }
}

// ---------------------------------------------------------------- launch
extern "C" void kernel_launch(void* const* d_in, const int* in_sizes, int n_in,
                              void* d_out, int out_size, void* d_ws, size_t ws_size,
                              hipStream_t stream) {
  const float* hidden = (const float*)d_in[0];
  const float* amask = (const float*)d_in[1];
  const float* Wq = (const float*)d_in[2];
  const float* bq = (const float*)d_in[3];
  const float* Wk = (const float*)d_in[4];
  const float* bk = (const float*)d_in[5];
  const float* Wv = (const float*)d_in[6];
  const float* bv = (const float*)d_in[7];
  const float* de = (const float*)d_in[8];
  float* outp = (float*)d_out;
  char* ws = (char*)d_ws;
  const size_t MB = 1024 * 1024;
  bf16_t* qb = (bf16_t*)(ws);             // 8 MiB [B,H,S,D]
  bf16_t* kb = (bf16_t*)(ws + 8 * MB);    // 8 MiB [B,H,S,D]
  bf16_t* vb = (bf16_t*)(ws + 16 * MB);   // 8 MiB [B,H,D,S]
  bf16_t* eb = (bf16_t*)(ws + 24 * MB);   // 512 KiB [4095,64]
  bf16_t* hb = (bf16_t*)(ws + 25 * MB);   // 8 MiB [4096,1024]
  bf16_t* wb = (bf16_t*)(ws + 33 * MB);   // 6 MiB [3][1024,1024]
  bf16_t* t1 = (bf16_t*)(ws + 40 * MB);   // 256 MiB [32,2048,2048]
  bf16_t* t2 = (bf16_t*)(ws + 296 * MB);  // 256 MiB
  const size_t NEED = 552 * MB;

  if (ws_size >= NEED) {
    cvt_e_kernel<<<dim3(1024), 256, 0, stream>>>(de, eb, 4095 * 64);
    cvt4_kernel<<<dim3(4096), 256, 0, stream>>>(hidden, hb, 4096 * 1024);
    cvt4_kernel<<<dim3(1024), 256, 0, stream>>>(Wq, wb, 1024 * 1024);
    cvt4_kernel<<<dim3(1024), 256, 0, stream>>>(Wk, wb + 1024 * 1024, 1024 * 1024);
    cvt4_kernel<<<dim3(1024), 256, 0, stream>>>(Wv, wb + 2 * 1024 * 1024, 1024 * 1024);
    qkv_gemm2_kernel<<<dim3(32, 8, 3), 256, 0, stream>>>(hb, wb, bq, bk, bv, qb, kb, vb);
    relq_kernel<<<dim3(32, 32), 256, 0, stream>>>(qb, eb, t1);
    relk_kernel<<<dim3(32, 32), 256, 0, stream>>>(kb, eb, t2);
    attn2_kernel<<<dim3(1024), 256, 0, stream>>>(qb, kb, vb, t1, t2, amask, outp);
  } else {
    cvt_e_kernel<<<dim3(1024), 256, 0, stream>>>(de, eb, 4095 * 64);
    dim3 g(32, 8);
    qkv_gemm_kernel<<<g, 256, 0, stream>>>(hidden, Wq, bq, qb, 0);
    qkv_gemm_kernel<<<g, 256, 0, stream>>>(hidden, Wk, bk, kb, 0);
    qkv_gemm_kernel<<<g, 256, 0, stream>>>(hidden, Wv, bv, vb, 1);
    attn_kernel<<<dim3(1024), 256, 0, stream>>>(qb, kb, vb, eb, amask, outp);
  }
}